// Round 10
// baseline (300.911 us; speedup 1.0000x reference)
//
#include <hip/hip_runtime.h>
#include <hip/hip_bf16.h>
#include <math.h>

#define NT   16384
#define DM   1024
#define NSEG 4
#define BK   64
#define HS   1024
#define TBLN 132

typedef __attribute__((ext_vector_type(8))) short bf16x8;
typedef __attribute__((ext_vector_type(4))) float f32x4;

typedef __attribute__((address_space(1))) unsigned int gu32;
typedef __attribute__((address_space(3))) unsigned int lu32;

__device__ __forceinline__ void gll16(const void* g, void* l) {
  __builtin_amdgcn_global_load_lds((gu32*)(unsigned long long)g,
                                   (lu32*)(unsigned int)(unsigned long long)l,
                                   16, 0, 0);
}

__device__ __forceinline__ unsigned short cvt_bf16(float f) {
  unsigned int u = __float_as_uint(f);
  u += 0x7fffu + ((u >> 16) & 1u);   // RNE
  return (unsigned short)(u >> 16);
}

// K0: 64-block scan (dtype detect + per-chunk seg counts).
__global__ __launch_bounds__(256) void k_scan(
    const int* __restrict__ idx, int* __restrict__ part) {
  __shared__ int sc[5];
  const int bid = blockIdx.x, tid = threadIdx.x;
  if (tid < 5) sc[tid] = 0;
  __syncthreads();
  int lane = tid & 63;
  int w32 = idx[bid * 256 + tid];               // in bounds for both dtypes
  unsigned long long m = __ballot((tid & 1) && (w32 != 0));
  if (lane == 0 && m) atomicAdd(&sc[4], 1);     // odd word nonzero => int32
  __syncthreads();
  int is32 = (sc[4] != 0);
  int s = w32;
  if (!is32) s = idx[bid * 512 + 2 * tid];      // only if genuinely int64
#pragma unroll
  for (int q = 0; q < 4; ++q) {
    m = __ballot(s == q);
    if (lane == 0 && m) atomicAdd(&sc[q], (int)__popcll(m));
  }
  __syncthreads();
  if (tid < 4) part[bid * 8 + tid] = sc[tid];
  if (tid == 4) part[bid * 8 + 4] = is32;
}

// K1 merged: blocks [0,2048) = rank + x compaction; [2048,5120) = weight
// transposes (independent of part => overlaps with the rank work).
__global__ __launch_bounds__(256) void k_prep(
    const int* __restrict__ idx, const int* __restrict__ part,
    const float4* __restrict__ x,
    int* __restrict__ meta, int2* __restrict__ table,
    int* __restrict__ perm, uint4* __restrict__ xc,
    const float* __restrict__ gw, const float* __restrict__ uw, const float* __restrict__ dw,
    unsigned short* __restrict__ gwt, unsigned short* __restrict__ uwt,
    unsigned short* __restrict__ dwt) {
  __shared__ float tile[64][65];
  __shared__ int cnt[64][4];
  __shared__ int wsum[4][4];
  __shared__ int tot[4], pref[4], gbase[4];
  __shared__ int rnk8[8];
  __shared__ int flag_s;
  const int tid = threadIdx.x;
  if (blockIdx.x >= 2048) {                       // ---- transpose role ----
    int tb = blockIdx.x - 2048;                   // 0..3071
    int mtx = tb >> 10, seg = (tb >> 8) & 3, tl = tb & 255;
    const float* src = (mtx == 0 ? gw : mtx == 1 ? uw : dw) + (size_t)seg * DM * HS;
    unsigned short* dst = (mtx == 0 ? gwt : mtx == 1 ? uwt : dwt) + (size_t)seg * DM * HS;
    int n0 = (tl & 15) * 64, k0 = (tl >> 4) * 64;
    int col = tid & 63, rb = tid >> 6;
#pragma unroll
    for (int i = 0; i < 64; i += 4)
      tile[i + rb][col] = src[(size_t)(k0 + i + rb) * 1024 + n0 + col];
    __syncthreads();
    int kp = tid & 31, nb = tid >> 5;
#pragma unroll
    for (int j = 0; j < 64; j += 8) {
      int nn = j + nb;
      unsigned int w = (unsigned)cvt_bf16(tile[2 * kp][nn]) |
                       ((unsigned)cvt_bf16(tile[2 * kp + 1][nn]) << 16);
      *(unsigned int*)(dst + (size_t)(n0 + nn) * 1024 + k0 + 2 * kp) = w;
    }
    return;
  }
  // ---- rank + compaction role ----
  const int bid = blockIdx.x;
  const int lane = tid & 63, wv = tid >> 6;
  const int c = bid >> 5;                 // chunk 0..63
  const int p0 = (bid & 31) * 8;          // target window within chunk

  if (tid == 0) flag_s = part[c * 8 + 4];
  if (wv == 0) {
#pragma unroll
    for (int s = 0; s < 4; ++s) cnt[lane][s] = part[lane * 8 + s];
  }
  __syncthreads();
  const int is32 = flag_s;
  int tok = c * 256 + tid;
  int s_t = is32 ? idx[tok] : idx[2 * tok];
  int myr = 0;
  unsigned long long lt = (1ull << lane) - 1;
#pragma unroll
  for (int q = 0; q < 4; ++q) {
    unsigned long long m = __ballot(s_t == q);
    if (lane == 0) wsum[wv][q] = (int)__popcll(m);
    if (s_t == q) myr = (int)__popcll(m & lt);
  }
  __syncthreads();
  if (tid < 4) {
    int s = tid, t = 0, p = 0;
    for (int b = 0; b < 64; ++b) { if (b == c) p = t; t += cnt[b][s]; }
    tot[s] = t; pref[s] = p;
  }
  __syncthreads();
  if (tid == 0) {
    gbase[0] = 0;
    for (int s = 1; s < 4; ++s) gbase[s] = gbase[s - 1] + tot[s - 1];
    if (bid == 0) {
      int nt = 0;
      for (int s = 0; s < 4; ++s) {
        meta[s] = tot[s]; meta[5 + s] = gbase[s];
        for (int m0 = 0; m0 < tot[s]; m0 += 128) table[nt++] = make_int2(s, m0);
      }
      for (; nt < TBLN; ++nt) table[nt] = make_int2(-1, 0);
    }
  }
  __syncthreads();
  int wpre = 0;
  for (int w2 = 0; w2 < wv; ++w2) wpre += wsum[w2][s_t];
  int r = gbase[s_t] + pref[s_t] + wpre + myr;
  if (tid >= p0 && tid < p0 + 8) {
    perm[r] = tok;
    rnk8[tid - p0] = r;
  }
  __syncthreads();
  // convert 8 tokens: 32 lanes per token, 1024 f32 each
  const int j = tid >> 5, l2 = tid & 31;
  const int tok8 = bid * 8 + j;
  const float4* src = x + (size_t)tok8 * 256;
  uint4* dst = xc + (size_t)rnk8[j] * 128;
#pragma unroll
  for (int it = 0; it < 4; ++it) {
    float4 a = src[it * 64 + l2 * 2];
    float4 b = src[it * 64 + l2 * 2 + 1];
    uint4 o;
    o.x = cvt_bf16(a.x) | ((unsigned)cvt_bf16(a.y) << 16);
    o.y = cvt_bf16(a.z) | ((unsigned)cvt_bf16(a.w) << 16);
    o.z = cvt_bf16(b.x) | ((unsigned)cvt_bf16(b.y) << 16);
    o.w = cvt_bf16(b.z) | ((unsigned)cvt_bf16(b.w) << 16);
    dst[it * 32 + l2] = o;
  }
}

// ---------------- counted-vmcnt pipeline helpers ----------------
#define WAITBAR_(N) \
  asm volatile("s_waitcnt vmcnt(" #N ") lgkmcnt(0)\n\ts_barrier" ::: "memory")
#define WAITBAR(N) WAITBAR_(N)

// Load a 2x2 fragment block (rows RB+{0,16}+fm, both K-halves) from LDS.
#define LDF(BUF, CUR, RB, F)                                               \
  F[0][0] = *(const bf16x8*)(&BUF[CUR][((RB) + fm) * 64] + x0);            \
  F[0][1] = *(const bf16x8*)(&BUF[CUR][((RB) + fm) * 64] + x1);            \
  F[1][0] = *(const bf16x8*)(&BUF[CUR][((RB) + 16 + fm) * 64] + x0);       \
  F[1][1] = *(const bf16x8*)(&BUF[CUR][((RB) + 16 + fm) * 64] + x1);

// 8 MFMA (2x2 frags x K=64) wrapped in setprio (T5).
#define MM8(ACC, MH, NH, AF, BF)                                                                                            \
  __builtin_amdgcn_s_setprio(1);                                                                                            \
  ACC[2*(MH)+0][2*(NH)+0] = __builtin_amdgcn_mfma_f32_16x16x32_bf16(AF[0][0], BF[0][0], ACC[2*(MH)+0][2*(NH)+0], 0, 0, 0);  \
  ACC[2*(MH)+0][2*(NH)+1] = __builtin_amdgcn_mfma_f32_16x16x32_bf16(AF[0][0], BF[1][0], ACC[2*(MH)+0][2*(NH)+1], 0, 0, 0);  \
  ACC[2*(MH)+1][2*(NH)+0] = __builtin_amdgcn_mfma_f32_16x16x32_bf16(AF[1][0], BF[0][0], ACC[2*(MH)+1][2*(NH)+0], 0, 0, 0);  \
  ACC[2*(MH)+1][2*(NH)+1] = __builtin_amdgcn_mfma_f32_16x16x32_bf16(AF[1][0], BF[1][0], ACC[2*(MH)+1][2*(NH)+1], 0, 0, 0);  \
  ACC[2*(MH)+0][2*(NH)+0] = __builtin_amdgcn_mfma_f32_16x16x32_bf16(AF[0][1], BF[0][1], ACC[2*(MH)+0][2*(NH)+0], 0, 0, 0);  \
  ACC[2*(MH)+0][2*(NH)+1] = __builtin_amdgcn_mfma_f32_16x16x32_bf16(AF[0][1], BF[1][1], ACC[2*(MH)+0][2*(NH)+1], 0, 0, 0);  \
  ACC[2*(MH)+1][2*(NH)+0] = __builtin_amdgcn_mfma_f32_16x16x32_bf16(AF[1][1], BF[0][1], ACC[2*(MH)+1][2*(NH)+0], 0, 0, 0);  \
  ACC[2*(MH)+1][2*(NH)+1] = __builtin_amdgcn_mfma_f32_16x16x32_bf16(AF[1][1], BF[1][1], ACC[2*(MH)+1][2*(NH)+1], 0, 0, 0);  \
  __builtin_amdgcn_s_setprio(0);

// ---------------- GEMM 1: gate+up fused, m97-class small block ----------------
// BM=128, N = 64 gate + 64 up, BK=64, 256 thr (4 waves, 2M x 2N).
// LDS = 48 KiB: A dbuf (32K), Bg/Bu single (8K+8K) => 3 blocks/CU.
// Per-thread issues/tile: [P1: a00,a01][P2: g0,g1][P3: a10,a11,u0,u1].
// FIFO waits: steady 6/2/6; epilogue 4/0/-.
__global__ __launch_bounds__(256) void k_gateup(
    const unsigned short* __restrict__ xc,
    const unsigned short* __restrict__ gwt,
    const unsigned short* __restrict__ uwt,
    const int* __restrict__ meta,
    const int2* __restrict__ table,
    unsigned short* __restrict__ hidden) {
  __shared__ __align__(16) unsigned short As[2][128 * 64];
  __shared__ __align__(16) unsigned short Bg[1][64 * 64];
  __shared__ __align__(16) unsigned short Bu[1][64 * 64];
  const int bid = blockIdx.x, tid = threadIdx.x;
  // XCD swizzle: grid = 16*TBLN = 2112 = 8*264 (bijective)
  const int lb = (bid & 7) * (16 * TBLN / 8) + (bid >> 3);
  const int2 te = table[lb >> 4];
  if (te.x < 0) return;
  const int seg = te.x, m0 = te.y;
  const int count = meta[seg], base = meta[5 + seg];
  const int n0 = (lb & 15) * 64;

  const int lane = tid & 63;
  const int wv = tid >> 6;                 // 4 waves
  const int l0 = lane >> 3, j = lane & 7;

  // A staging: A0-slot = rows {0-31, 64-95}; A1-slot = +32.
  const int rb0 = wv * 8;                  // rows 0..31 group
  const int rb1 = wv * 8 + 64;             // rows 64..95 group
  const int a00d = rb0 * 128, a01d = rb1 * 128;
  const int a10d = a00d + 32 * 128, a11d = a01d + 32 * 128;
  const int r00 = rb0 + l0, r01 = rb1 + l0;
  const int r10 = r00 + 32, r11 = r01 + 32;
  auto rowof = [&](int r) { int g = m0 + r; return g < count ? g : count - 1; };
  const unsigned short* a00p = xc + (size_t)(base + rowof(r00)) * DM + (j ^ (r00 & 7)) * 8;
  const unsigned short* a01p = xc + (size_t)(base + rowof(r01)) * DM + (j ^ (r01 & 7)) * 8;
  const unsigned short* a10p = xc + (size_t)(base + rowof(r10)) * DM + (j ^ (r10 & 7)) * 8;
  const unsigned short* a11p = xc + (size_t)(base + rowof(r11)) * DM + (j ^ (r11 & 7)) * 8;
  // B staging: issue0 rows 0-31, issue1 rows 32-63 (linear).
  const int gb0 = wv * 8, gb1 = wv * 8 + 32;
  const int g0d = gb0 * 128, g1d = gb1 * 128;
  const int gr0 = gb0 + l0, gr1 = gb1 + l0;
  const unsigned short* gp0 = gwt + (size_t)(seg * HS + n0 + gr0) * DM + (j ^ (gr0 & 7)) * 8;
  const unsigned short* gp1 = gwt + (size_t)(seg * HS + n0 + gr1) * DM + (j ^ (gr1 & 7)) * 8;
  const unsigned short* up0 = uwt + (size_t)(seg * HS + n0 + gr0) * DM + (j ^ (gr0 & 7)) * 8;
  const unsigned short* up1 = uwt + (size_t)(seg * HS + n0 + gr1) * DM + (j ^ (gr1 & 7)) * 8;

  const int mw = (wv & 1) * 64;            // 2 M-waves
  const int nw = (wv >> 1) * 32;           // 2 N-waves
  const int fm = lane & 15, fq = lane >> 4;
  const int x0 = (fq ^ (fm & 7)) * 8;
  const int x1 = ((4 + fq) ^ (fm & 7)) * 8;

  f32x4 accg[4][2] = {};
  f32x4 accu[4][2] = {};

#define GU_ITER(CUR, NXT) {                                   \
    bf16x8 af[2][2], af2[2][2], bg2[2][2], bu2[2][2];         \
    gll16(a00p, (char*)&As[NXT][0] + a00d);                   \
    gll16(a01p, (char*)&As[NXT][0] + a01d);                   \
    WAITBAR(6);                                               \
    LDF(As, CUR, mw, af); LDF(Bg, 0, nw, bg2);                \
    MM8(accg, 0, 0, af, bg2);                                 \
    WAITBAR(2);                                               \
    LDF(Bu, 0, nw, bu2);                                      \
    gll16(gp0, (char*)&Bg[0][0] + g0d);                       \
    gll16(gp1, (char*)&Bg[0][0] + g1d);                       \
    MM8(accu, 0, 0, af, bu2);                                 \
    WAITBAR(6);                                               \
    LDF(As, CUR, mw + 32, af2);                               \
    gll16(a10p, (char*)&As[NXT][0] + a10d);                   \
    gll16(a11p, (char*)&As[NXT][0] + a11d);                   \
    gll16(up0, (char*)&Bu[0][0] + g0d);                       \
    gll16(up1, (char*)&Bu[0][0] + g1d);                       \
    MM8(accg, 1, 0, af2, bg2);                                \
    MM8(accu, 1, 0, af2, bu2);                                \
    a00p += BK; a01p += BK; a10p += BK; a11p += BK;           \
    gp0 += BK; gp1 += BK; up0 += BK; up1 += BK;               \
  }

  // prologue: stage tile 0 in slot order a00,a01,g0,g1,a10,a11,u0,u1
  gll16(a00p, (char*)&As[0][0] + a00d);
  gll16(a01p, (char*)&As[0][0] + a01d);
  gll16(gp0,  (char*)&Bg[0][0] + g0d);
  gll16(gp1,  (char*)&Bg[0][0] + g1d);
  gll16(a10p, (char*)&As[0][0] + a10d);
  gll16(a11p, (char*)&As[0][0] + a11d);
  gll16(up0,  (char*)&Bu[0][0] + g0d);
  gll16(up1,  (char*)&Bu[0][0] + g1d);
  a00p += BK; a01p += BK; a10p += BK; a11p += BK;
  gp0 += BK; gp1 += BK; up0 += BK; up1 += BK;

#pragma unroll 1
  for (int t7 = 0; t7 < 7; ++t7) {
    GU_ITER(0, 1);
    GU_ITER(1, 0);
  }
  GU_ITER(0, 1);
  {  // epilogue K-tile 15 (CUR=1; fully staged during tile 14)
    bf16x8 af[2][2], af2[2][2], bg2[2][2], bu2[2][2];
    WAITBAR(4);
    LDF(As, 1, mw, af); LDF(Bg, 0, nw, bg2);
    MM8(accg, 0, 0, af, bg2);
    WAITBAR(0);
    LDF(Bu, 0, nw, bu2);
    MM8(accu, 0, 0, af, bu2);
    LDF(As, 1, mw + 32, af2);
    MM8(accg, 1, 0, af2, bg2);
    MM8(accu, 1, 0, af2, bu2);
  }
#undef GU_ITER

  const int rq = fq * 4;
#pragma unroll
  for (int mi = 0; mi < 4; ++mi) {
#pragma unroll
    for (int r = 0; r < 4; ++r) {
      int row = m0 + mw + mi * 16 + rq + r;
      if (row < count) {
        unsigned short* h = hidden + (size_t)(base + row) * HS + n0 + nw;
#pragma unroll
        for (int ni = 0; ni < 2; ++ni) {
          float gv = accg[mi][ni][r];
          float uv = accu[mi][ni][r];
          float sig = 1.0f / (1.0f + __expf(-gv));
          h[ni * 16 + fm] = cvt_bf16(gv * sig * uv);
        }
      }
    }
  }
}

// ---------------- GEMM 2: down, m97-class small block ----------------
// BM=128, BN=64, BK=64, 256 thr (4 waves, 2M x 2N).
// LDS = 48 KiB: A dbuf (32K) + B dbuf (16K) => 3 blocks/CU.
// Issues/tile: [P1: a00,a01][P2: a10,a11,b0,b1]; waits steady 2/4; epi 0.
__global__ __launch_bounds__(256) void k_down(
    const unsigned short* __restrict__ hidden,
    const unsigned short* __restrict__ dwt,
    const int* __restrict__ meta,
    const int2* __restrict__ table,
    const int* __restrict__ perm,
    float* __restrict__ out) {
  __shared__ __align__(16) unsigned short As[2][128 * 64];
  __shared__ __align__(16) unsigned short Bs[2][64 * 64];
  const int bid = blockIdx.x, tid = threadIdx.x;
  // XCD swizzle: grid = 16*TBLN = 2112 = 8*264 (bijective)
  const int lb = (bid & 7) * (16 * TBLN / 8) + (bid >> 3);
  const int2 te = table[lb >> 4];
  if (te.x < 0) return;
  const int seg = te.x, m0 = te.y;
  const int count = meta[seg], base = meta[5 + seg];
  const int n0 = (lb & 15) * 64;

  const int lane = tid & 63;
  const int wv = tid >> 6;
  const int l0 = lane >> 3, j = lane & 7;

  const int rb0 = wv * 8;
  const int rb1 = wv * 8 + 64;
  const int a00d = rb0 * 128, a01d = rb1 * 128;
  const int a10d = a00d + 32 * 128, a11d = a01d + 32 * 128;
  const int r00 = rb0 + l0, r01 = rb1 + l0;
  const int r10 = r00 + 32, r11 = r01 + 32;
  auto rowof = [&](int r) { int g = m0 + r; return g < count ? g : count - 1; };
  const unsigned short* a00p = hidden + (size_t)(base + rowof(r00)) * HS + (j ^ (r00 & 7)) * 8;
  const unsigned short* a01p = hidden + (size_t)(base + rowof(r01)) * HS + (j ^ (r01 & 7)) * 8;
  const unsigned short* a10p = hidden + (size_t)(base + rowof(r10)) * HS + (j ^ (r10 & 7)) * 8;
  const unsigned short* a11p = hidden + (size_t)(base + rowof(r11)) * HS + (j ^ (r11 & 7)) * 8;
  const int bb0 = wv * 8, bb1 = wv * 8 + 32;
  const int b0d = bb0 * 128, b1d = bb1 * 128;
  const int br0 = bb0 + l0, br1 = bb1 + l0;
  const unsigned short* bp0 = dwt + (size_t)(seg * DM + n0 + br0) * HS + (j ^ (br0 & 7)) * 8;
  const unsigned short* bp1 = dwt + (size_t)(seg * DM + n0 + br1) * HS + (j ^ (br1 & 7)) * 8;

  const int mw = (wv & 1) * 64;            // 2 M-waves
  const int nw = (wv >> 1) * 32;           // 2 N-waves
  const int fm = lane & 15, fq = lane >> 4;
  const int x0 = (fq ^ (fm & 7)) * 8;
  const int x1 = ((4 + fq) ^ (fm & 7)) * 8;

  f32x4 acc[4][2] = {};

#define DN_ITER(CUR, NXT) {                                   \
    bf16x8 af[2][2], af2[2][2], b[2][2];                      \
    gll16(a00p, (char*)&As[NXT][0] + a00d);                   \
    gll16(a01p, (char*)&As[NXT][0] + a01d);                   \
    WAITBAR(2);                                               \
    LDF(As, CUR, mw, af); LDF(Bs, CUR, nw, b);                \
    MM8(acc, 0, 0, af, b);                                    \
    WAITBAR(4);                                               \
    LDF(As, CUR, mw + 32, af2);                               \
    gll16(a10p, (char*)&As[NXT][0] + a10d);                   \
    gll16(a11p, (char*)&As[NXT][0] + a11d);                   \
    gll16(bp0, (char*)&Bs[NXT][0] + b0d);                     \
    gll16(bp1, (char*)&Bs[NXT][0] + b1d);                     \
    MM8(acc, 1, 0, af2, b);                                   \
    a00p += BK; a01p += BK; a10p += BK; a11p += BK;           \
    bp0 += BK; bp1 += BK;                                     \
  }

  // prologue: stage tile 0 in slot order a00,a01,a10,a11,b0,b1
  gll16(a00p, (char*)&As[0][0] + a00d);
  gll16(a01p, (char*)&As[0][0] + a01d);
  gll16(a10p, (char*)&As[0][0] + a10d);
  gll16(a11p, (char*)&As[0][0] + a11d);
  gll16(bp0,  (char*)&Bs[0][0] + b0d);
  gll16(bp1,  (char*)&Bs[0][0] + b1d);
  a00p += BK; a01p += BK; a10p += BK; a11p += BK;
  bp0 += BK; bp1 += BK;

#pragma unroll 1
  for (int t7 = 0; t7 < 7; ++t7) {
    DN_ITER(0, 1);
    DN_ITER(1, 0);
  }
  DN_ITER(0, 1);
  {  // epilogue K-tile 15 (CUR=1; fully staged during tile 14)
    bf16x8 af[2][2], af2[2][2], b[2][2];
    WAITBAR(0);
    LDF(As, 1, mw, af); LDF(Bs, 1, nw, b);
    MM8(acc, 0, 0, af, b);
    LDF(As, 1, mw + 32, af2);
    MM8(acc, 1, 0, af2, b);
  }
#undef DN_ITER

  const int rq = fq * 4;
#pragma unroll
  for (int mi = 0; mi < 4; ++mi) {
#pragma unroll
    for (int r = 0; r < 4; ++r) {
      int row = m0 + mw + mi * 16 + rq + r;
      if (row < count) {
        int t = perm[base + row];
        float* o = out + (size_t)t * DM + n0 + nw;
#pragma unroll
        for (int ni = 0; ni < 2; ++ni)
          o[ni * 16 + fm] = acc[mi][ni][r];
      }
    }
  }
}

// ---------------- launch ----------------

extern "C" void kernel_launch(void* const* d_in, const int* in_sizes, int n_in,
                              void* d_out, int out_size, void* d_ws, size_t ws_size,
                              hipStream_t stream) {
  const float* x  = (const float*)d_in[0];
  const float* gw = (const float*)d_in[1];
  const float* uw = (const float*)d_in[2];
  const float* dw = (const float*)d_in[3];
  const int* tsi  = (const int*)d_in[4];
  float* out = (float*)d_out;

  char* ws = (char*)d_ws;
  int*  meta  = (int*)ws;                        // 64 ints
  int*  part  = (int*)(ws + 256);                // 64*8 ints
  int2* table = (int2*)(ws + 4096);              // TBLN entries
  int*  perm  = (int*)(ws + 8192);               // NT ints (64 KiB)
  unsigned short* xc  = (unsigned short*)(ws + (1 << 18));  // 32 MiB compacted
  unsigned short* gwt = xc + (size_t)NT * DM;               // 8 MiB
  unsigned short* uwt = gwt + (size_t)NSEG * HS * DM;       // 8 MiB
  unsigned short* dwt = uwt + (size_t)NSEG * HS * DM;       // 8 MiB
  unsigned short* hid = dwt + (size_t)NSEG * DM * HS;       // 32 MiB compacted

  k_scan<<<64, 256, 0, stream>>>(tsi, part);
  k_prep<<<2048 + 3072, 256, 0, stream>>>(tsi, part, (const float4*)x, meta, table,
                                          perm, (uint4*)xc, gw, uw, dw, gwt, uwt, dwt);
  k_gateup<<<16 * TBLN, 256, 0, stream>>>(xc, gwt, uwt, meta, table, hid);
  k_down<<<16 * TBLN, 256, 0, stream>>>(hid, dwt, meta, table, perm, out);
}